// Round 1
// 1115.291 us; speedup vs baseline: 1.1053x; 1.1053x over previous
//
#include <hip/hip_runtime.h>

// ---------------------------------------------------------------------------
// update_v (PDN-GNN) on MI355X / gfx950.  All float I/O fp32.
//
// R4 changes vs R3 (1232 us):
//  - activations stored as SPLIT bf16 hi/lo planes (same bytes as fp32);
//    k_gemm stages all 4 operand planes via global_load_lds dwordx4 with a
//    128B-super-row XOR swizzle (pre-swizzled per-lane source + swizzled
//    ds_read) -> zero staging VALU, conflict-free fragment reads, LDS 32KB
//  - k_gather/k_segsum: lane-batched index prefetch (shfl broadcast) +
//    8-deep double-buffered row pipeline (16 outstanding loads/wave)
//  - k_final fused into lins3 GEMM epilogue (atomicAdd into zeroed d_out)
//  - k_cntm merged into k_edge; scanA/scanC pairs merged (grid.y);
//    4x k_splitw merged into one launch.  18 launches total.
// Numerics identical to R3 (same 3-term split, moved producer-side).
//
// Workspace layout (bytes), total 117,866,656 (<= R3's 117,867,264):
//   edgep  0            12,800,000   (int2 row+norm per edge, CSR by col)
//   Xh     12,800,000   16,000,000 \  aliased by s0h/s0l (Xcat dead by lin_up)
//   Xl     28,800,000   16,000,000 /
//   s0h    12,800,000   25,600,000
//   s0l    38,400,000   25,600,000
//   v1h    64,000,000   12,800,000 \  aliased by s1h/s1l (dead by lins1)
//   v1l    76,800,000   12,800,000 |
//   xw     89,600,000   12,800,000 /
//   s1h    64,000,000   25,600,000
//   s1l    89,600,000   25,600,000
//   ew     102,400,000  6,400,000    (s1l tail; dead before s1 written)
//   midx   108,800,000  2,400,000    (s1l tail; dead early)
//   cntC   115,200,000  200,000  \
//   cntM   115,400,000  200,000   } memset together
//   deg    115,600,000  200,000  /
//   offC   115,800,000  200,064
//   curC   116,000,064  200,000
//   offM   116,200,064  200,064
//   curM   116,400,128  200,000
//   dinv   116,600,128  200,000
//   Wh     116,800,128  532,480
//   Wl     117,332,608  532,480
//   partC  117,865,088  784
//   partM  117,865,872  784
// ---------------------------------------------------------------------------

#define Nn 50000
#define Mm 600000
#define Ee 1600000
#define NB 196          // ceil(Nn/256)

typedef unsigned short u16;
typedef unsigned int u32;
typedef __attribute__((ext_vector_type(8))) short bh8;   // 8 bf16 = 4 VGPRs
typedef __attribute__((ext_vector_type(4))) float f4;    // 4 fp32 acc

__device__ __forceinline__ float bf2f(u16 u) {
    union { u32 i; float f; } v; v.i = ((u32)u) << 16; return v.f;
}
__device__ __forceinline__ u16 f2bf(float f) {   // RNE, finite inputs
    union { float f; u32 u; } v; v.f = f;
    return (u16)((v.u + 0x7fffu + ((v.u >> 16) & 1u)) >> 16);
}
// async global->LDS, 16B per lane; LDS dest = wave-uniform base + lane*16
__device__ __forceinline__ void gload16(const void* g, void* l) {
    __builtin_amdgcn_global_load_lds(
        (const __attribute__((address_space(1))) void*)g,
        (__attribute__((address_space(3))) void*)l, 16, 0, 0);
}

// --------------------------- edge MLP + degree + cntM ----------------------
__global__ __launch_bounds__(256) void k_edge(
    const float* __restrict__ attr, const int* __restrict__ eidx,
    const float* __restrict__ w1, const float* __restrict__ b1,
    const float* __restrict__ w2, const float* __restrict__ b2,
    float* __restrict__ ew, float* __restrict__ deg, int* __restrict__ cntC,
    const int* __restrict__ ii, int* __restrict__ cntM)
{
    __shared__ float sW1[64], sB1[8], sW2[8], sB2;
    int t = threadIdx.x;
    int e = blockIdx.x * 256 + t;
    if (e < Mm) atomicAdd(&cntM[ii[e]], 1);     // merged k_cntm
    if (t < 64) sW1[t] = w1[t];
    if (t < 8) { sB1[t] = b1[t]; sW2[t] = w2[t]; }
    if (t == 0) sB2 = b2[0];
    __syncthreads();
    if (e >= Ee) return;                         // grid is exact: vacuous
    float4 q0 = *(const float4*)(attr + (size_t)e * 8);
    float4 q1 = *(const float4*)(attr + (size_t)e * 8 + 4);
    float a[8] = { q0.x, q0.y, q0.z, q0.w, q1.x, q1.y, q1.z, q1.w };
    float z = sB2;
#pragma unroll
    for (int j = 0; j < 8; ++j) {
        float h = sB1[j];
#pragma unroll
        for (int k = 0; k < 8; ++k) h += a[k] * sW1[j * 8 + k];
        z += fmaxf(h, 0.f) * sW2[j];
    }
    float s = 1.f / (1.f + __expf(-z));
    ew[e] = s;
    int c = eidx[Ee + e];
    atomicAdd(&deg[c], s);
    atomicAdd(&cntC[c], 1);
}

// --------------------- 3-phase multi-block exclusive scan ------------------
// kA: per-block local exclusive scan into `loc`, block total into `part`
// grid = (NB, 2): y==0 -> C arrays, y==1 -> M arrays
__global__ __launch_bounds__(256) void k_scanA(
    const int* __restrict__ cntC, int* __restrict__ locC, int* __restrict__ partC,
    const int* __restrict__ cntM, int* __restrict__ locM, int* __restrict__ partM)
{
    const int* cnt = blockIdx.y ? cntM : cntC;
    int* loc  = blockIdx.y ? locM : locC;
    int* part = blockIdx.y ? partM : partC;
    __shared__ int buf[256];
    int t = threadIdx.x, i = blockIdx.x * 256 + t;
    int v = (i < Nn) ? cnt[i] : 0;
    buf[t] = v;
    __syncthreads();
#pragma unroll
    for (int d = 1; d < 256; d <<= 1) {
        int x = (t >= d) ? buf[t - d] : 0;
        __syncthreads();
        buf[t] += x;
        __syncthreads();
    }
    if (i < Nn) loc[i] = buf[t] - v;        // local exclusive
    if (t == 255) part[blockIdx.x] = buf[255];
}

// kB: exclusive-scan the NB partials (block 0 -> pA, block 1 -> pB)
__global__ __launch_bounds__(256) void k_scanB(int* __restrict__ pA,
                                               int* __restrict__ pB)
{
    int* p = blockIdx.x ? pB : pA;
    __shared__ int buf[256];
    int t = threadIdx.x;
    int v = (t < NB) ? p[t] : 0;
    buf[t] = v;
    __syncthreads();
#pragma unroll
    for (int d = 1; d < 256; d <<= 1) {
        int x = (t >= d) ? buf[t - d] : 0;
        __syncthreads();
        buf[t] += x;
        __syncthreads();
    }
    if (t < NB) p[t] = buf[t] - v;
}

// kC: off = loc + part[b]; cur = off; off[Nn] = total; dinv on y==0
__global__ __launch_bounds__(256) void k_scanC(
    const int* __restrict__ cntC, const int* __restrict__ partC,
    int* __restrict__ offC, int* __restrict__ curC,
    const int* __restrict__ cntM, const int* __restrict__ partM,
    int* __restrict__ offM, int* __restrict__ curM,
    const float* __restrict__ deg, float* __restrict__ dinv)
{
    int t = threadIdx.x, i = blockIdx.x * 256 + t;
    if (i >= Nn) return;
    const int* cnt  = blockIdx.y ? cntM : cntC;
    const int* part = blockIdx.y ? partM : partC;
    int* off = blockIdx.y ? offM : offC;
    int* cur = blockIdx.y ? curM : curC;
    int v = off[i] + part[blockIdx.x];
    off[i] = v;
    cur[i] = v;
    if (i == Nn - 1) off[Nn] = v + cnt[i];
    if (!blockIdx.y) {
        float d = deg[i];
        dinv[i] = (d > 0.f) ? rsqrtf(fmaxf(d, 1e-30f)) : 0.f;
    }
}

// --------------------------- CSR scatter -----------------------------------
__global__ __launch_bounds__(256) void k_scatter_col(
    const int* __restrict__ eidx, const float* __restrict__ ew,
    const float* __restrict__ dinv, int* __restrict__ cur,
    int2* __restrict__ edgep)
{
    int e = blockIdx.x * 256 + threadIdx.x;
    if (e >= Ee) return;
    int r = eidx[e], c = eidx[Ee + e];
    float nm = dinv[r] * ew[e] * dinv[c];
    int idx = atomicAdd(&cur[c], 1);       // cur starts at offC -> absolute
    edgep[idx] = make_int2(r, __float_as_int(nm));
}

__global__ __launch_bounds__(256) void k_scatter_m(
    const int* __restrict__ ii, int* __restrict__ cur, int* __restrict__ midx)
{
    int m = blockIdx.x * 256 + threadIdx.x;
    if (m >= Mm) return;
    midx[atomicAdd(&cur[ii[m]], 1)] = m;
}

// --------------------------- e2 segment sum -> X planes --------------------
// wave-per-node; per 64-edge batch each lane preloads one midx, shfl
// broadcast; row loads 8-deep double-buffered (16 outstanding / wave).
#define SLD1(dst, tt) { int _m = __shfl(mm, (tt), 64); \
    dst = *(const float2*)(e2 + (size_t)_m * 128 + (lane << 1)); }
#define SLD8(P, base) { SLD1(P##0, base+0); SLD1(P##1, base+1); \
    SLD1(P##2, base+2); SLD1(P##3, base+3); SLD1(P##4, base+4); \
    SLD1(P##5, base+5); SLD1(P##6, base+6); SLD1(P##7, base+7); }
#define SFM1(sv, tt) { if (b + (tt) < j1) { a0 += sv.x; a1 += sv.y; } }
#define SFM8(P, base) { SFM1(P##0, base+0); SFM1(P##1, base+1); \
    SFM1(P##2, base+2); SFM1(P##3, base+3); SFM1(P##4, base+4); \
    SFM1(P##5, base+5); SFM1(P##6, base+6); SFM1(P##7, base+7); }

__global__ __launch_bounds__(256) void k_segsum(
    const int* __restrict__ offM, const int* __restrict__ midx,
    const float* __restrict__ e2, const float* __restrict__ afe,
    u16* __restrict__ xh, u16* __restrict__ xl)
{
    int wv = threadIdx.x >> 6, lane = threadIdx.x & 63;
    int n = blockIdx.x * 4 + wv;
    if (n >= Nn) return;
    int j0 = offM[n], j1 = offM[n + 1];
    float a0 = 0.f, a1 = 0.f;
    for (int b = j0; b < j1; b += 64) {
        int mm = (b + lane < j1) ? midx[b + lane] : 0;   // pad -> row 0 (safe)
        int nb = j1 - b;
        float2 A0,A1,A2,A3,A4,A5,A6,A7, B0,B1,B2,B3,B4,B5,B6,B7;
        SLD8(A, 0);
        if (nb > 8) { SLD8(B, 8); SFM8(A, 0);
          if (nb > 16) { SLD8(A, 16); SFM8(B, 8);
            if (nb > 24) { SLD8(B, 24); SFM8(A, 16);
              if (nb > 32) { SLD8(A, 32); SFM8(B, 24);
                if (nb > 40) { SLD8(B, 40); SFM8(A, 32);
                  if (nb > 48) { SLD8(A, 48); SFM8(B, 40);
                    if (nb > 56) { SLD8(B, 56); SFM8(A, 48); SFM8(B, 56); }
                    else { SFM8(A, 48); }
                  } else { SFM8(B, 40); }
                } else { SFM8(A, 32); }
              } else { SFM8(B, 24); }
            } else { SFM8(A, 16); }
          } else { SFM8(B, 8); }
        } else { SFM8(A, 0); }
    }
    u16 h0 = f2bf(a0), h1 = f2bf(a1);
    u16 l0 = f2bf(a0 - bf2f(h0)), l1 = f2bf(a1 - bf2f(h1));
    *(u32*)(xh + (size_t)n * 160 + lane * 2) = (u32)h0 | ((u32)h1 << 16);
    *(u32*)(xl + (size_t)n * 160 + lane * 2) = (u32)l0 | ((u32)l1 << 16);
    if (lane < 16) {                       // channels 128..159: afe then pad 0
        int c0 = 2 * lane, c1 = 2 * lane + 1;
        float v0 = (c0 < 7) ? afe[(size_t)n * 7 + c0] : 0.f;
        float v1 = (c1 < 7) ? afe[(size_t)n * 7 + c1] : 0.f;
        u16 vh0 = f2bf(v0), vh1 = f2bf(v1);
        u16 vl0 = f2bf(v0 - bf2f(vh0)), vl1 = f2bf(v1 - bf2f(vh1));
        *(u32*)(xh + (size_t)n * 160 + 128 + lane * 2) = (u32)vh0 | ((u32)vh1 << 16);
        *(u32*)(xl + (size_t)n * 160 + 128 + lane * 2) = (u32)vl0 | ((u32)vl1 << 16);
    }
}
#undef SLD1
#undef SLD8
#undef SFM1
#undef SFM8

// --------------------------- weight split (merged, fp32 -> bf16 hi+lo) -----
__global__ __launch_bounds__(256) void k_splitw_all(
    const float* __restrict__ wv_, const float* __restrict__ wc_,
    const float* __restrict__ wu_, const float* __restrict__ wl_,
    u16* __restrict__ h, u16* __restrict__ l)
{
    int idx = blockIdx.x * 256 + threadIdx.x;
    if (idx >= 266240) return;
    const float* src; int sc, dc, loc;
    if (idx < 20480)      { src = wv_; sc = 135; dc = 160; loc = idx; }
    else if (idx < 36864) { src = wc_; sc = 128; dc = 128; loc = idx - 20480; }
    else if (idx < 69632) { src = wu_; sc = 128; dc = 128; loc = idx - 36864; }
    else                  { src = wl_; sc = 256; dc = 256; loc = idx - 69632; }
    int r = loc / dc, c = loc - r * dc;
    float x = (c < sc) ? src[(size_t)r * sc + c] : 0.f;
    u16 hh = f2bf(x);
    h[idx] = hh;
    l[idx] = f2bf(x - bf2f(hh));
}

// --------------------------- split MFMA GEMM -------------------------------
// Y[M,NO] = op(A[M,K] @ B[NO,K]^T + bias), all operands pre-split bf16 hi/lo
// planes.  acc += Ah*Bh + Al*Bh + Ah*Bl (~fp32 exact, err ~2^-18).
// Tile 128x128, BK=32, 4 waves (2x2 of 64x64), 16x16x32 MFMA.
// Staging: wave wv DMAs plane wv (Ah/Al/Bh/Bl) via 8x global_load_lds
// dwordx4/lane.  LDS layout: 64 super-rows x 128B; chunk c of super-row S
// holds logical (row 2S+rho, k-quarter q) with {rho,q} = decode(c ^ (S&7)).
// Source per-lane address applies the same permutation (rule 21), read
// applies it again -> bank-conflict-free (<=2-way) ds_read_b128.
// flags: 1=relu, 2=also write lo plane, 4=fused final dot (lw, atomicAdd out)
__global__ __launch_bounds__(256) void k_gemm(
    const u16* __restrict__ Ah_, const u16* __restrict__ Al_,
    const u16* __restrict__ Bh_, const u16* __restrict__ Bl_,
    const float* __restrict__ bias,
    u16* __restrict__ Yh, u16* __restrict__ Yl,
    const float* __restrict__ lw, float* __restrict__ outv,
    int M, int K, int NO, int flags)
{
    __shared__ __align__(16) u16 sL[4][4096];    // Ah, Al, Bh, Bl : 8KB each
    const int t = threadIdx.x;
    const int lane = t & 63, wv = t >> 6;
    const int m0 = blockIdx.x * 128, n0 = blockIdx.y * 128;
    const int lr = lane & 15, lq = lane >> 4;
    const int wm = (wv >> 1) * 64, wn = (wv & 1) * 64;

    // staging: lane -> (super-row sl, chunk chv) of a 1KB wave-load
    const int sl = lane >> 3, chv = lane & 7;
    const int uu = chv ^ sl, rho = uu >> 2, qq = uu & 3;
    const u16* gbase = (wv == 0) ? Ah_ : (wv == 1) ? Al_ : (wv == 2) ? Bh_ : Bl_;
    const int rbase = (wv < 2) ? m0 : n0;
    const u16* src[8];
#pragma unroll
    for (int rg = 0; rg < 8; ++rg) {
        int rr = rbase + rg * 16 + 2 * sl + rho;
        if (wv < 2 && rr > M - 1) rr = M - 1;    // clamp: dup rows only feed
        src[rg] = gbase + (size_t)rr * K + qq * 8;   // discarded gm >= M
    }
    u16* dst = sL[wv];

    // fragment LDS offsets (u16 units), k-invariant -> hoisted
    int offA[4], offB[4];
#pragma unroll
    for (int i = 0; i < 4; ++i) {
        int ra = wm + i * 16 + lr;
        offA[i] = (ra >> 1) * 64 + ((((ra & 1) << 2) | lq) ^ ((ra >> 1) & 7)) * 8;
        int rb = wn + i * 16 + lr;
        offB[i] = (rb >> 1) * 64 + ((((rb & 1) << 2) | lq) ^ ((rb >> 1) & 7)) * 8;
    }
    const u16* sAh = sL[0]; const u16* sAl = sL[1];
    const u16* sBh = sL[2]; const u16* sBl = sL[3];

    f4 acc[4][4] = {};
    for (int k0 = 0; k0 < K; k0 += 32) {
#pragma unroll
        for (int rg = 0; rg < 8; ++rg) {
            gload16(src[rg], dst + rg * 512);
            src[rg] += 32;
        }
        __syncthreads();                 // drains vmcnt -> LDS tile ready
        bh8 fah[4], fal[4], fbh[4], fbl[4];
#pragma unroll
        for (int i = 0; i < 4; ++i) {
            fah[i] = *(const bh8*)(sAh + offA[i]);
            fal[i] = *(const bh8*)(sAl + offA[i]);
            fbh[i] = *(const bh8*)(sBh + offB[i]);
            fbl[i] = *(const bh8*)(sBl + offB[i]);
        }
#pragma unroll
        for (int mi = 0; mi < 4; ++mi)
#pragma unroll
            for (int ni = 0; ni < 4; ++ni) {
                acc[mi][ni] = __builtin_amdgcn_mfma_f32_16x16x32_bf16(
                    fah[mi], fbh[ni], acc[mi][ni], 0, 0, 0);
                acc[mi][ni] = __builtin_amdgcn_mfma_f32_16x16x32_bf16(
                    fal[mi], fbh[ni], acc[mi][ni], 0, 0, 0);
                acc[mi][ni] = __builtin_amdgcn_mfma_f32_16x16x32_bf16(
                    fah[mi], fbl[ni], acc[mi][ni], 0, 0, 0);
            }
        __syncthreads();                 // all reads done before overwrite
    }

    if (flags & 4) {                     // fused final: out = relu(Y) @ lw^T
        float lwv[4], bvv[4];
#pragma unroll
        for (int ni = 0; ni < 4; ++ni) {
            int gn = n0 + wn + ni * 16 + lr;
            lwv[ni] = lw[gn];
            bvv[ni] = bias[gn];
        }
#pragma unroll
        for (int mi = 0; mi < 4; ++mi)
#pragma unroll
            for (int r = 0; r < 4; ++r) {
                float s = 0.f;
#pragma unroll
                for (int ni = 0; ni < 4; ++ni) {
                    float v = acc[mi][ni][r] + bvv[ni];
                    if (flags & 1) v = fmaxf(v, 0.f);
                    s = fmaf(v, lwv[ni], s);
                }
                s += __shfl_xor(s, 1, 64);
                s += __shfl_xor(s, 2, 64);
                s += __shfl_xor(s, 4, 64);
                s += __shfl_xor(s, 8, 64);
                int gm = m0 + wm + mi * 16 + lq * 4 + r;
                if (lr == 0 && gm < M) atomicAdd(outv + gm, s);
            }
        return;
    }
#pragma unroll
    for (int ni = 0; ni < 4; ++ni) {
        int gn = n0 + wn + ni * 16 + lr;
        float bv = bias ? bias[gn] : 0.f;
#pragma unroll
        for (int mi = 0; mi < 4; ++mi) {
#pragma unroll
            for (int r = 0; r < 4; ++r) {
                int gm = m0 + wm + mi * 16 + lq * 4 + r;
                if (gm < M) {
                    float v = acc[mi][ni][r] + bv;
                    if (flags & 1) v = fmaxf(v, 0.f);
                    u16 hh = f2bf(v);
                    Yh[(size_t)gm * NO + gn] = hh;
                    if (flags & 2) Yl[(size_t)gm * NO + gn] = f2bf(v - bf2f(hh));
                }
            }
        }
    }
}

// --------------------------- conv gather (CSR by col) ----------------------
// wave-per-node; per 64-edge batch each lane preloads one (row,norm) int2,
// shfl broadcast; xw row loads 8-deep double-buffered.  Pad lanes carry
// w=0 and row=0 -> contribute nothing, loads safe.
#define GLD1(dst, tt) { int _r = __shfl(my.x, (tt), 64); \
    dst = *(const u32*)(xw + (size_t)_r * 128 + (lane << 1)); }
#define GLD8(P, base) { GLD1(P##0, base+0); GLD1(P##1, base+1); \
    GLD1(P##2, base+2); GLD1(P##3, base+3); GLD1(P##4, base+4); \
    GLD1(P##5, base+5); GLD1(P##6, base+6); GLD1(P##7, base+7); }
#define GFM1(sv, tt) { float _w = __int_as_float(__shfl(my.y, (tt), 64)); \
    a0 = fmaf(_w, bf2f((u16)(sv & 0xffffu)), a0); \
    a1 = fmaf(_w, bf2f((u16)(sv >> 16)), a1); }
#define GFM8(P, base) { GFM1(P##0, base+0); GFM1(P##1, base+1); \
    GFM1(P##2, base+2); GFM1(P##3, base+3); GFM1(P##4, base+4); \
    GFM1(P##5, base+5); GFM1(P##6, base+6); GFM1(P##7, base+7); }

__global__ __launch_bounds__(256) void k_gather(
    const int* __restrict__ off, const int2* __restrict__ edgep,
    const u16* __restrict__ xw, u16* __restrict__ oh, u16* __restrict__ ol,
    int relu)
{
    int wv = threadIdx.x >> 6, lane = threadIdx.x & 63;
    int n = blockIdx.x * 4 + wv;
    if (n >= Nn) return;
    int j0 = off[n], j1 = off[n + 1];
    float a0 = 0.f, a1 = 0.f;
    for (int b = j0; b < j1; b += 64) {
        int2 my = (b + lane < j1) ? edgep[b + lane] : make_int2(0, 0);
        int nb = j1 - b;
        u32 A0,A1,A2,A3,A4,A5,A6,A7, B0,B1,B2,B3,B4,B5,B6,B7;
        GLD8(A, 0);
        if (nb > 8) { GLD8(B, 8); GFM8(A, 0);
          if (nb > 16) { GLD8(A, 16); GFM8(B, 8);
            if (nb > 24) { GLD8(B, 24); GFM8(A, 16);
              if (nb > 32) { GLD8(A, 32); GFM8(B, 24);
                if (nb > 40) { GLD8(B, 40); GFM8(A, 32);
                  if (nb > 48) { GLD8(A, 48); GFM8(B, 40);
                    if (nb > 56) { GLD8(B, 56); GFM8(A, 48); GFM8(B, 56); }
                    else { GFM8(A, 48); }
                  } else { GFM8(B, 40); }
                } else { GFM8(A, 32); }
              } else { GFM8(B, 24); }
            } else { GFM8(A, 16); }
          } else { GFM8(B, 8); }
        } else { GFM8(A, 0); }
    }
    if (relu) { a0 = fmaxf(a0, 0.f); a1 = fmaxf(a1, 0.f); }
    u16 h0 = f2bf(a0), h1 = f2bf(a1);
    u16 l0 = f2bf(a0 - bf2f(h0)), l1 = f2bf(a1 - bf2f(h1));
    *(u32*)(oh + (size_t)n * 128 + lane * 2) = (u32)h0 | ((u32)h1 << 16);
    *(u32*)(ol + (size_t)n * 128 + lane * 2) = (u32)l0 | ((u32)l1 << 16);
}
#undef GLD1
#undef GLD8
#undef GFM1
#undef GFM8

// ---------------------------------------------------------------------------
extern "C" void kernel_launch(void* const* d_in, const int* in_sizes, int n_in,
                              void* d_out, int out_size, void* d_ws, size_t ws_size,
                              hipStream_t stream)
{
    (void)in_sizes; (void)n_in; (void)out_size; (void)ws_size;
    const float* e2       = (const float*)d_in[0];
    const int*   iidx     = (const int*)d_in[1];
    const float* afe      = (const float*)d_in[2];
    const int*   bei      = (const int*)d_in[3];
    const float* battr    = (const float*)d_in[4];
    const float* lin_v_w  = (const float*)d_in[5];
    const float* lin_v_b  = (const float*)d_in[6];
    const float* conv_w   = (const float*)d_in[7];
    const float* w1       = (const float*)d_in[8];
    const float* b1       = (const float*)d_in[9];
    const float* w2       = (const float*)d_in[10];
    const float* b2       = (const float*)d_in[11];
    const float* lin_up_w = (const float*)d_in[12];
    const float* lin_up_b = (const float*)d_in[13];
    const float* lins_w   = (const float*)d_in[14];
    const float* lins_b   = (const float*)d_in[15];
    const float* lin_w    = (const float*)d_in[16];

    char* ws = (char*)d_ws;
    int2* edgep = (int2*)(ws + 0);
    u16*  Xh    = (u16*) (ws + 12800000);
    u16*  Xl    = (u16*) (ws + 28800000);
    u16*  s0h   = (u16*) (ws + 12800000);       // alias (Xcat dead by lin_up)
    u16*  s0l   = (u16*) (ws + 38400000);
    u16*  v1h   = (u16*) (ws + 64000000);
    u16*  v1l   = (u16*) (ws + 76800000);
    u16*  xw    = (u16*) (ws + 89600000);
    u16*  s1h   = (u16*) (ws + 64000000);       // alias (v1,xw dead by lins1)
    u16*  s1l   = (u16*) (ws + 89600000);
    float* ew   = (float*)(ws + 102400000);     // s1l tail; dead early
    int*   midx = (int*)  (ws + 108800000);     // s1l tail; dead early
    int*   cntC = (int*)  (ws + 115200000);
    int*   cntM = (int*)  (ws + 115400000);
    float* deg  = (float*)(ws + 115600000);
    int*   offC = (int*)  (ws + 115800000);
    int*   curC = (int*)  (ws + 116000064);
    int*   offM = (int*)  (ws + 116200064);
    int*   curM = (int*)  (ws + 116400128);
    float* dinv = (float*)(ws + 116600128);
    u16*   Wh   = (u16*)  (ws + 116800128);     // 266,240 elements
    u16*   Wl   = (u16*)  (ws + 117332608);
    int*   partC= (int*)  (ws + 117865088);
    int*   partM= (int*)  (ws + 117865872);

    // Wh/Wl element offsets per matrix:
    const int oWv = 0, oConv = 20480, oLup = 36864, oLins = 69632;

    hipMemsetAsync(ws + 115200000, 0, 3 * Nn * 4, stream);   // cntC,cntM,deg
    hipMemsetAsync(d_out, 0, Nn * 4, stream);                // fused-final acc

    k_edge<<<(Ee + 255) / 256, 256, 0, stream>>>(battr, bei, w1, b1, w2, b2,
                                                 ew, deg, cntC, iidx, cntM);
    k_scanA<<<dim3(NB, 2), 256, 0, stream>>>(cntC, offC, partC,
                                             cntM, offM, partM);
    k_scanB<<<2, 256, 0, stream>>>(partC, partM);
    k_scanC<<<dim3(NB, 2), 256, 0, stream>>>(cntC, partC, offC, curC,
                                             cntM, partM, offM, curM,
                                             deg, dinv);
    k_scatter_col<<<(Ee + 255) / 256, 256, 0, stream>>>(bei, ew, dinv, curC,
                                                        edgep);
    k_scatter_m<<<(Mm + 255) / 256, 256, 0, stream>>>(iidx, curM, midx);
    k_segsum<<<(Nn + 3) / 4, 256, 0, stream>>>(offM, midx, e2, afe, Xh, Xl);
    k_splitw_all<<<(266240 + 255) / 256, 256, 0, stream>>>(
        lin_v_w, conv_w, lin_up_w, lins_w, Wh, Wl);

#define GEMM(AH, AL, WO, BP, YH, YL, LW, OV, M_, K_, NO_, FL_)                \
    k_gemm<<<dim3(((M_) + 127) / 128, (NO_) / 128), 256, 0, stream>>>(        \
        AH, AL, Wh + (WO), Wl + (WO), (const float*)(BP),                     \
        YH, YL, (const float*)(LW), (float*)(OV), M_, K_, NO_, FL_)

    GEMM(Xh, Xl, oWv, lin_v_b, v1h, v1l, nullptr, nullptr, Nn, 160, 128, 2);
    GEMM(v1h, v1l, oConv, nullptr, xw, nullptr, nullptr, nullptr,
         Nn, 128, 128, 0);                                     // xw1 bf16
    k_gather<<<(Nn + 3) / 4, 256, 0, stream>>>(offC, edgep, xw, v1h, v1l, 0);
    GEMM(v1h, v1l, oConv, nullptr, xw, nullptr, nullptr, nullptr,
         Nn, 128, 128, 0);                                     // xw2 bf16
    k_gather<<<(Nn + 3) / 4, 256, 0, stream>>>(offC, edgep, xw, v1h, v1l, 1);
    GEMM(v1h, v1l, oLup, lin_up_b, s0h, s0l, nullptr, nullptr,
         Nn, 128, 256, 2);                                     // lin_up
    GEMM(s0h, s0l, oLins + 0 * 65536, lins_b + 0,   s1h, s1l, nullptr, nullptr,
         Nn, 256, 256, 3);
    GEMM(s1h, s1l, oLins + 1 * 65536, lins_b + 256, s0h, s0l, nullptr, nullptr,
         Nn, 256, 256, 3);
    GEMM(s0h, s0l, oLins + 2 * 65536, lins_b + 512, nullptr, nullptr,
         lin_w, d_out, Nn, 256, 256, 5);                       // fused final
#undef GEMM
}

// Round 3
// 1036.893 us; speedup vs baseline: 1.1888x; 1.0756x over previous
//
#include <hip/hip_runtime.h>

// ---------------------------------------------------------------------------
// update_v (PDN-GNN) on MI355X / gfx950.  All float I/O fp32.
//
// R5 (resubmit; previous attempt hit GPUAcquisitionTimeout, never ran).
// Changes vs R4 (1115 us):
//  - k_gemm k-loop double-buffered with COUNTED vmcnt (s_waitcnt vmcnt(8) +
//    raw s_barrier): next tile's global_load_lds stays in flight across the
//    barrier instead of a full drain every K-step.  LDS 32 -> 64 KB.
//  - k_gemm epilogue: acc -> fp32 LDS tile (64x132) -> row-major readback ->
//    uint4 stores (64B-contiguous segments vs 32B scattered u16 stores)
//  - k_scatter_col + k_scatter_m merged (17 dispatches total)
// Numerics identical to R4 (same 3-term bf16 split, same rounding path).
//
// Workspace layout (bytes), total 117,866,656:
//   edgep  0            12,800,000   (int2 row+norm per edge, CSR by col)
//   Xh     12,800,000   16,000,000 \  aliased by s0h/s0l (Xcat dead by lin_up)
//   Xl     28,800,000   16,000,000 /
//   s0h    12,800,000   25,600,000
//   s0l    38,400,000   25,600,000
//   v1h    64,000,000   12,800,000 \  aliased by s1h/s1l (dead by lins1)
//   v1l    76,800,000   12,800,000 |
//   xw     89,600,000   12,800,000 /
//   s1h    64,000,000   25,600,000
//   s1l    89,600,000   25,600,000
//   ew     102,400,000  6,400,000    (s1l tail; dead before s1 written)
//   midx   108,800,000  2,400,000    (s1l tail; dead early)
//   cntC   115,200,000  200,000  \
//   cntM   115,400,000  200,000   } memset together
//   deg    115,600,000  200,000  /
//   offC   115,800,000  200,064
//   curC   116,000,064  200,000
//   offM   116,200,064  200,064
//   curM   116,400,128  200,000
//   dinv   116,600,128  200,000
//   Wh     116,800,128  532,480
//   Wl     117,332,608  532,480
//   partC  117,865,088  784
//   partM  117,865,872  784
// ---------------------------------------------------------------------------

#define Nn 50000
#define Mm 600000
#define Ee 1600000
#define NB 196          // ceil(Nn/256)

typedef unsigned short u16;
typedef unsigned int u32;
typedef __attribute__((ext_vector_type(8))) short bh8;   // 8 bf16 = 4 VGPRs
typedef __attribute__((ext_vector_type(4))) float f4;    // 4 fp32 acc

__device__ __forceinline__ float bf2f(u16 u) {
    union { u32 i; float f; } v; v.i = ((u32)u) << 16; return v.f;
}
__device__ __forceinline__ u16 f2bf(float f) {   // RNE, finite inputs
    union { float f; u32 u; } v; v.f = f;
    return (u16)((v.u + 0x7fffu + ((v.u >> 16) & 1u)) >> 16);
}
// async global->LDS, 16B per lane; LDS dest = wave-uniform base + lane*16
__device__ __forceinline__ void gload16(const void* g, void* l) {
    __builtin_amdgcn_global_load_lds(
        (const __attribute__((address_space(1))) void*)g,
        (__attribute__((address_space(3))) void*)l, 16, 0, 0);
}

// --------------------------- edge MLP + degree + cntM ----------------------
__global__ __launch_bounds__(256) void k_edge(
    const float* __restrict__ attr, const int* __restrict__ eidx,
    const float* __restrict__ w1, const float* __restrict__ b1,
    const float* __restrict__ w2, const float* __restrict__ b2,
    float* __restrict__ ew, float* __restrict__ deg, int* __restrict__ cntC,
    const int* __restrict__ ii, int* __restrict__ cntM)
{
    __shared__ float sW1[64], sB1[8], sW2[8], sB2;
    int t = threadIdx.x;
    int e = blockIdx.x * 256 + t;
    if (e < Mm) atomicAdd(&cntM[ii[e]], 1);     // merged k_cntm
    if (t < 64) sW1[t] = w1[t];
    if (t < 8) { sB1[t] = b1[t]; sW2[t] = w2[t]; }
    if (t == 0) sB2 = b2[0];
    __syncthreads();
    if (e >= Ee) return;                         // grid is exact: vacuous
    float4 q0 = *(const float4*)(attr + (size_t)e * 8);
    float4 q1 = *(const float4*)(attr + (size_t)e * 8 + 4);
    float a[8] = { q0.x, q0.y, q0.z, q0.w, q1.x, q1.y, q1.z, q1.w };
    float z = sB2;
#pragma unroll
    for (int j = 0; j < 8; ++j) {
        float h = sB1[j];
#pragma unroll
        for (int k = 0; k < 8; ++k) h += a[k] * sW1[j * 8 + k];
        z += fmaxf(h, 0.f) * sW2[j];
    }
    float s = 1.f / (1.f + __expf(-z));
    ew[e] = s;
    int c = eidx[Ee + e];
    atomicAdd(&deg[c], s);
    atomicAdd(&cntC[c], 1);
}

// --------------------- 3-phase multi-block exclusive scan ------------------
// kA: per-block local exclusive scan into `loc`, block total into `part`
// grid = (NB, 2): y==0 -> C arrays, y==1 -> M arrays
__global__ __launch_bounds__(256) void k_scanA(
    const int* __restrict__ cntC, int* __restrict__ locC, int* __restrict__ partC,
    const int* __restrict__ cntM, int* __restrict__ locM, int* __restrict__ partM)
{
    const int* cnt = blockIdx.y ? cntM : cntC;
    int* loc  = blockIdx.y ? locM : locC;
    int* part = blockIdx.y ? partM : partC;
    __shared__ int buf[256];
    int t = threadIdx.x, i = blockIdx.x * 256 + t;
    int v = (i < Nn) ? cnt[i] : 0;
    buf[t] = v;
    __syncthreads();
#pragma unroll
    for (int d = 1; d < 256; d <<= 1) {
        int x = (t >= d) ? buf[t - d] : 0;
        __syncthreads();
        buf[t] += x;
        __syncthreads();
    }
    if (i < Nn) loc[i] = buf[t] - v;        // local exclusive
    if (t == 255) part[blockIdx.x] = buf[255];
}

// kB: exclusive-scan the NB partials (block 0 -> pA, block 1 -> pB)
__global__ __launch_bounds__(256) void k_scanB(int* __restrict__ pA,
                                               int* __restrict__ pB)
{
    int* p = blockIdx.x ? pB : pA;
    __shared__ int buf[256];
    int t = threadIdx.x;
    int v = (t < NB) ? p[t] : 0;
    buf[t] = v;
    __syncthreads();
#pragma unroll
    for (int d = 1; d < 256; d <<= 1) {
        int x = (t >= d) ? buf[t - d] : 0;
        __syncthreads();
        buf[t] += x;
        __syncthreads();
    }
    if (t < NB) p[t] = buf[t] - v;
}

// kC: off = loc + part[b]; cur = off; off[Nn] = total; dinv on y==0
__global__ __launch_bounds__(256) void k_scanC(
    const int* __restrict__ cntC, const int* __restrict__ partC,
    int* __restrict__ offC, int* __restrict__ curC,
    const int* __restrict__ cntM, const int* __restrict__ partM,
    int* __restrict__ offM, int* __restrict__ curM,
    const float* __restrict__ deg, float* __restrict__ dinv)
{
    int t = threadIdx.x, i = blockIdx.x * 256 + t;
    if (i >= Nn) return;
    const int* cnt  = blockIdx.y ? cntM : cntC;
    const int* part = blockIdx.y ? partM : partC;
    int* off = blockIdx.y ? offM : offC;
    int* cur = blockIdx.y ? curM : curC;
    int v = off[i] + part[blockIdx.x];
    off[i] = v;
    cur[i] = v;
    if (i == Nn - 1) off[Nn] = v + cnt[i];
    if (!blockIdx.y) {
        float d = deg[i];
        dinv[i] = (d > 0.f) ? rsqrtf(fmaxf(d, 1e-30f)) : 0.f;
    }
}

// --------------------------- CSR scatter (merged col + m) ------------------
__global__ __launch_bounds__(256) void k_scatter(
    const int* __restrict__ eidx, const float* __restrict__ ew,
    const float* __restrict__ dinv, int* __restrict__ curC,
    int2* __restrict__ edgep,
    const int* __restrict__ ii, int* __restrict__ curM, int* __restrict__ midx)
{
    int e = blockIdx.x * 256 + threadIdx.x;
    if (e < Mm) midx[atomicAdd(&curM[ii[e]], 1)] = e;
    if (e >= Ee) return;
    int r = eidx[e], c = eidx[Ee + e];
    float nm = dinv[r] * ew[e] * dinv[c];
    int idx = atomicAdd(&curC[c], 1);      // cur starts at offC -> absolute
    edgep[idx] = make_int2(r, __float_as_int(nm));
}

// --------------------------- e2 segment sum -> X planes --------------------
// wave-per-node; per 64-edge batch each lane preloads one midx, shfl
// broadcast; row loads 8-deep double-buffered (16 outstanding / wave).
#define SLD1(dst, tt) { int _m = __shfl(mm, (tt), 64); \
    dst = *(const float2*)(e2 + (size_t)_m * 128 + (lane << 1)); }
#define SLD8(P, base) { SLD1(P##0, base+0); SLD1(P##1, base+1); \
    SLD1(P##2, base+2); SLD1(P##3, base+3); SLD1(P##4, base+4); \
    SLD1(P##5, base+5); SLD1(P##6, base+6); SLD1(P##7, base+7); }
#define SFM1(sv, tt) { if (b + (tt) < j1) { a0 += sv.x; a1 += sv.y; } }
#define SFM8(P, base) { SFM1(P##0, base+0); SFM1(P##1, base+1); \
    SFM1(P##2, base+2); SFM1(P##3, base+3); SFM1(P##4, base+4); \
    SFM1(P##5, base+5); SFM1(P##6, base+6); SFM1(P##7, base+7); }

__global__ __launch_bounds__(256) void k_segsum(
    const int* __restrict__ offM, const int* __restrict__ midx,
    const float* __restrict__ e2, const float* __restrict__ afe,
    u16* __restrict__ xh, u16* __restrict__ xl)
{
    int wv = threadIdx.x >> 6, lane = threadIdx.x & 63;
    int n = blockIdx.x * 4 + wv;
    if (n >= Nn) return;
    int j0 = offM[n], j1 = offM[n + 1];
    float a0 = 0.f, a1 = 0.f;
    for (int b = j0; b < j1; b += 64) {
        int mm = (b + lane < j1) ? midx[b + lane] : 0;   // pad -> row 0 (safe)
        int nb = j1 - b;
        float2 A0,A1,A2,A3,A4,A5,A6,A7, B0,B1,B2,B3,B4,B5,B6,B7;
        SLD8(A, 0);
        if (nb > 8) { SLD8(B, 8); SFM8(A, 0);
          if (nb > 16) { SLD8(A, 16); SFM8(B, 8);
            if (nb > 24) { SLD8(B, 24); SFM8(A, 16);
              if (nb > 32) { SLD8(A, 32); SFM8(B, 24);
                if (nb > 40) { SLD8(B, 40); SFM8(A, 32);
                  if (nb > 48) { SLD8(A, 48); SFM8(B, 40);
                    if (nb > 56) { SLD8(B, 56); SFM8(A, 48); SFM8(B, 56); }
                    else { SFM8(A, 48); }
                  } else { SFM8(B, 40); }
                } else { SFM8(A, 32); }
              } else { SFM8(B, 24); }
            } else { SFM8(A, 16); }
          } else { SFM8(B, 8); }
        } else { SFM8(A, 0); }
    }
    u16 h0 = f2bf(a0), h1 = f2bf(a1);
    u16 l0 = f2bf(a0 - bf2f(h0)), l1 = f2bf(a1 - bf2f(h1));
    *(u32*)(xh + (size_t)n * 160 + lane * 2) = (u32)h0 | ((u32)h1 << 16);
    *(u32*)(xl + (size_t)n * 160 + lane * 2) = (u32)l0 | ((u32)l1 << 16);
    if (lane < 16) {                       // channels 128..159: afe then pad 0
        int c0 = 2 * lane, c1 = 2 * lane + 1;
        float v0 = (c0 < 7) ? afe[(size_t)n * 7 + c0] : 0.f;
        float v1 = (c1 < 7) ? afe[(size_t)n * 7 + c1] : 0.f;
        u16 vh0 = f2bf(v0), vh1 = f2bf(v1);
        u16 vl0 = f2bf(v0 - bf2f(vh0)), vl1 = f2bf(v1 - bf2f(vh1));
        *(u32*)(xh + (size_t)n * 160 + 128 + lane * 2) = (u32)vh0 | ((u32)vh1 << 16);
        *(u32*)(xl + (size_t)n * 160 + 128 + lane * 2) = (u32)vl0 | ((u32)vl1 << 16);
    }
}
#undef SLD1
#undef SLD8
#undef SFM1
#undef SFM8

// --------------------------- weight split (merged, fp32 -> bf16 hi+lo) -----
__global__ __launch_bounds__(256) void k_splitw_all(
    const float* __restrict__ wv_, const float* __restrict__ wc_,
    const float* __restrict__ wu_, const float* __restrict__ wl_,
    u16* __restrict__ h, u16* __restrict__ l)
{
    int idx = blockIdx.x * 256 + threadIdx.x;
    if (idx >= 266240) return;
    const float* src; int sc, dc, loc;
    if (idx < 20480)      { src = wv_; sc = 135; dc = 160; loc = idx; }
    else if (idx < 36864) { src = wc_; sc = 128; dc = 128; loc = idx - 20480; }
    else if (idx < 69632) { src = wu_; sc = 128; dc = 128; loc = idx - 36864; }
    else                  { src = wl_; sc = 256; dc = 256; loc = idx - 69632; }
    int r = loc / dc, c = loc - r * dc;
    float x = (c < sc) ? src[(size_t)r * sc + c] : 0.f;
    u16 hh = f2bf(x);
    h[idx] = hh;
    l[idx] = f2bf(x - bf2f(hh));
}

// --------------------------- split MFMA GEMM -------------------------------
// Y[M,NO] = op(A[M,K] @ B[NO,K]^T + bias), all operands pre-split bf16 hi/lo
// planes.  acc += Ah*Bh + Al*Bh + Ah*Bl (~fp32 exact, err ~2^-18).
// Tile 128x128, BK=32, 4 waves (2x2 of 64x64), 16x16x32 MFMA.
// Staging: DOUBLE-BUFFERED.  Wave wv DMAs plane wv (Ah/Al/Bh/Bl) via 8x
// global_load_lds dwordx4/lane into sL[buf]; tile t+1 issued before tile t
// is consumed, with s_waitcnt vmcnt(8) (counted, never 0 mid-loop) + raw
// s_barrier -> next tile's loads stay in flight across the barrier.
// LDS swizzle (rule 21, both-sides): 64 super-rows x 128B; chunk c of
// super-row S holds logical (row 2S+rho, k-quarter q), {rho,q}=decode(c^(S&7))
// applied at the per-lane global source AND at the ds_read offsets.
// Epilogue: acc -> fp32 LDS (64x132, 2-way-free banks) -> row-major uint4
// stores of hi/lo bf16 planes (64B segments).
// flags: 1=relu, 2=also write lo plane, 4=fused final dot (lw, atomicAdd out)
__global__ __launch_bounds__(256) void k_gemm(
    const u16* __restrict__ Ah_, const u16* __restrict__ Al_,
    const u16* __restrict__ Bh_, const u16* __restrict__ Bl_,
    const float* __restrict__ bias,
    u16* __restrict__ Yh, u16* __restrict__ Yl,
    const float* __restrict__ lw, float* __restrict__ outv,
    int M, int K, int NO, int flags)
{
    __shared__ __align__(16) u16 sL[2][4][4096];   // 2 bufs x 4 planes x 8KB
    const int t = threadIdx.x;
    const int lane = t & 63, wv = t >> 6;
    const int m0 = blockIdx.x * 128, n0 = blockIdx.y * 128;
    const int lr = lane & 15, lq = lane >> 4;
    const int wm = (wv >> 1) * 64, wn = (wv & 1) * 64;

    // staging: lane -> (super-row sl, chunk chv) of a 1KB wave-load
    const int sl = lane >> 3, chv = lane & 7;
    const int uu = chv ^ sl, rho = uu >> 2, qq = uu & 3;
    const u16* gbase = (wv == 0) ? Ah_ : (wv == 1) ? Al_ : (wv == 2) ? Bh_ : Bl_;
    const int rbase = (wv < 2) ? m0 : n0;
    const u16* src[8];
#pragma unroll
    for (int rg = 0; rg < 8; ++rg) {
        int rr = rbase + rg * 16 + 2 * sl + rho;
        if (wv < 2 && rr > M - 1) rr = M - 1;    // clamp: dup rows only feed
        src[rg] = gbase + (size_t)rr * K + qq * 8;   // discarded gm >= M
    }

    // fragment LDS offsets (u16 units), k-invariant -> hoisted
    int offA[4], offB[4];
#pragma unroll
    for (int i = 0; i < 4; ++i) {
        int ra = wm + i * 16 + lr;
        offA[i] = (ra >> 1) * 64 + ((((ra & 1) << 2) | lq) ^ ((ra >> 1) & 7)) * 8;
        int rb = wn + i * 16 + lr;
        offB[i] = (rb >> 1) * 64 + ((((rb & 1) << 2) | lq) ^ ((rb >> 1) & 7)) * 8;
    }

#define STAGE(BUF) do { u16* _d = &sL[BUF][wv][0];                            \
    _Pragma("unroll")                                                         \
    for (int rg = 0; rg < 8; ++rg) { gload16(src[rg], _d + rg * 512);         \
                                     src[rg] += 32; } } while (0)

    f4 acc[4][4] = {};
    const int nt = K >> 5;
    STAGE(0);                            // prologue: tile 0 in flight (vm=8)
    for (int tt = 0; tt < nt; ++tt) {
        const int cur = tt & 1;
        if (tt + 1 < nt) {
            STAGE(cur ^ 1);              // issue next tile (vm=16)
            asm volatile("s_waitcnt vmcnt(8)" ::: "memory");  // tile tt ready
        } else {
            asm volatile("s_waitcnt vmcnt(0)" ::: "memory");
        }
        __builtin_amdgcn_s_barrier();    // all waves: tile tt staged
        const u16* sb = &sL[cur][0][0];
        bh8 fah[4], fal[4], fbh[4], fbl[4];
#pragma unroll
        for (int i = 0; i < 4; ++i) {
            fah[i] = *(const bh8*)(sb +         offA[i]);
            fal[i] = *(const bh8*)(sb + 4096  + offA[i]);
            fbh[i] = *(const bh8*)(sb + 8192  + offB[i]);
            fbl[i] = *(const bh8*)(sb + 12288 + offB[i]);
        }
#pragma unroll
        for (int mi = 0; mi < 4; ++mi)
#pragma unroll
            for (int ni = 0; ni < 4; ++ni) {
                acc[mi][ni] = __builtin_amdgcn_mfma_f32_16x16x32_bf16(
                    fah[mi], fbh[ni], acc[mi][ni], 0, 0, 0);
                acc[mi][ni] = __builtin_amdgcn_mfma_f32_16x16x32_bf16(
                    fal[mi], fbh[ni], acc[mi][ni], 0, 0, 0);
                acc[mi][ni] = __builtin_amdgcn_mfma_f32_16x16x32_bf16(
                    fah[mi], fbl[ni], acc[mi][ni], 0, 0, 0);
            }
        __builtin_amdgcn_s_barrier();    // reads done; next STAGE may overwrite
    }
#undef STAGE

    if (flags & 4) {                     // fused final: out = relu(Y) @ lw^T
        float lwv[4], bvv[4];
#pragma unroll
        for (int ni = 0; ni < 4; ++ni) {
            int gn = n0 + wn + ni * 16 + lr;
            lwv[ni] = lw[gn];
            bvv[ni] = bias[gn];
        }
#pragma unroll
        for (int mi = 0; mi < 4; ++mi)
#pragma unroll
            for (int r = 0; r < 4; ++r) {
                float s = 0.f;
#pragma unroll
                for (int ni = 0; ni < 4; ++ni) {
                    float v = acc[mi][ni][r] + bvv[ni];
                    if (flags & 1) v = fmaxf(v, 0.f);
                    s = fmaf(v, lwv[ni], s);
                }
                s += __shfl_xor(s, 1, 64);
                s += __shfl_xor(s, 2, 64);
                s += __shfl_xor(s, 4, 64);
                s += __shfl_xor(s, 8, 64);
                int gm = m0 + wm + mi * 16 + lq * 4 + r;
                if (lr == 0 && gm < M) atomicAdd(outv + gm, s);
            }
        return;
    }

    // ---------- LDS-transpose epilogue: fp32 tile -> coalesced bf16 stores --
    float* sT = (float*)&sL[0][0][0];    // 64 x 132 f32 = 33,792 B (of 64 KB)
    float bvv[4];
#pragma unroll
    for (int ni = 0; ni < 4; ++ni)
        bvv[ni] = bias ? bias[n0 + wn + ni * 16 + lr] : 0.f;
    const int row_r = t >> 2;            // 0..63  read/store role
    const int c0 = (t & 3) * 8;
#pragma unroll
    for (int half = 0; half < 2; ++half) {
        __syncthreads();                 // LDS free (prev phase reads done)
        if ((wv >> 1) == half) {
#pragma unroll
            for (int mi = 0; mi < 4; ++mi)
#pragma unroll
                for (int ni = 0; ni < 4; ++ni)
#pragma unroll
                    for (int r = 0; r < 4; ++r) {
                        float v = acc[mi][ni][r] + bvv[ni];
                        if (flags & 1) v = fmaxf(v, 0.f);
                        sT[(mi * 16 + lq * 4 + r) * 132 + wn + ni * 16 + lr] = v;
                    }
        }
        __syncthreads();
        int gr = m0 + half * 64 + row_r;
        if (gr < M) {
#pragma unroll
            for (int kq = 0; kq < 4; ++kq) {
                const float* p = sT + row_r * 132 + c0 + kq * 32;
                float4 u0 = *(const float4*)p;
                float4 u1 = *(const float4*)(p + 4);
                float vv[8] = { u0.x, u0.y, u0.z, u0.w,
                                u1.x, u1.y, u1.z, u1.w };
                union { u16 s[8]; uint4 q; } H, L;
#pragma unroll
                for (int j = 0; j < 8; ++j) {
                    u16 hh = f2bf(vv[j]);
                    H.s[j] = hh;
                    L.s[j] = f2bf(vv[j] - bf2f(hh));
                }
                size_t off = (size_t)gr * NO + n0 + c0 + kq * 32;
                *(uint4*)(Yh + off) = H.q;
                if (flags & 2) *(uint4*)(Yl + off) = L.q;
            }
        }
    }
}

// --------------------------- conv gather (CSR by col) ----------------------
// wave-per-node; per 64-edge batch each lane preloads one (row,norm) int2,
// shfl broadcast; xw row loads 8-deep double-buffered.  Pad lanes carry
// w=0 and row=0 -> contribute nothing, loads safe.
#define GLD1(dst, tt) { int _r = __shfl(my.x, (tt), 64); \
    dst = *(const u32*)(xw + (size_t)_r * 128 + (lane << 1)); }
#define GLD8(P, base) { GLD1(P##0, base+0); GLD1(P##1, base+1); \
    GLD1(P##2, base+2); GLD1(P##3, base+3); GLD1(P##4, base+4); \
    GLD1(P##5, base+5); GLD1(P##6, base+6); GLD1(P##7, base+7); }
#define GFM1(sv, tt) { float _w = __int_as_float(__shfl(my.y, (tt), 64)); \
    a0 = fmaf(_w, bf2f((u16)(sv & 0xffffu)), a0); \
    a1 = fmaf(_w, bf2f((u16)(sv >> 16)), a1); }
#define GFM8(P, base) { GFM1(P##0, base+0); GFM1(P##1, base+1); \
    GFM1(P##2, base+2); GFM1(P##3, base+3); GFM1(P##4, base+4); \
    GFM1(P##5, base+5); GFM1(P##6, base+6); GFM1(P##7, base+7); }

__global__ __launch_bounds__(256) void k_gather(
    const int* __restrict__ off, const int2* __restrict__ edgep,
    const u16* __restrict__ xw, u16* __restrict__ oh, u16* __restrict__ ol,
    int relu)
{
    int wv = threadIdx.x >> 6, lane = threadIdx.x & 63;
    int n = blockIdx.x * 4 + wv;
    if (n >= Nn) return;
    int j0 = off[n], j1 = off[n + 1];
    float a0 = 0.f, a1 = 0.f;
    for (int b = j0; b < j1; b += 64) {
        int2 my = (b + lane < j1) ? edgep[b + lane] : make_int2(0, 0);
        int nb = j1 - b;
        u32 A0,A1,A2,A3,A4,A5,A6,A7, B0,B1,B2,B3,B4,B5,B6,B7;
        GLD8(A, 0);
        if (nb > 8) { GLD8(B, 8); GFM8(A, 0);
          if (nb > 16) { GLD8(A, 16); GFM8(B, 8);
            if (nb > 24) { GLD8(B, 24); GFM8(A, 16);
              if (nb > 32) { GLD8(A, 32); GFM8(B, 24);
                if (nb > 40) { GLD8(B, 40); GFM8(A, 32);
                  if (nb > 48) { GLD8(A, 48); GFM8(B, 40);
                    if (nb > 56) { GLD8(B, 56); GFM8(A, 48); GFM8(B, 56); }
                    else { GFM8(A, 48); }
                  } else { GFM8(B, 40); }
                } else { GFM8(A, 32); }
              } else { GFM8(B, 24); }
            } else { GFM8(A, 16); }
          } else { GFM8(B, 8); }
        } else { GFM8(A, 0); }
    }
    if (relu) { a0 = fmaxf(a0, 0.f); a1 = fmaxf(a1, 0.f); }
    u16 h0 = f2bf(a0), h1 = f2bf(a1);
    u16 l0 = f2bf(a0 - bf2f(h0)), l1 = f2bf(a1 - bf2f(h1));
    *(u32*)(oh + (size_t)n * 128 + lane * 2) = (u32)h0 | ((u32)h1 << 16);
    *(u32*)(ol + (size_t)n * 128 + lane * 2) = (u32)l0 | ((u32)l1 << 16);
}
#undef GLD1
#undef GLD8
#undef GFM1
#undef GFM8

// ---------------------------------------------------------------------------
extern "C" void kernel_launch(void* const* d_in, const int* in_sizes, int n_in,
                              void* d_out, int out_size, void* d_ws, size_t ws_size,
                              hipStream_t stream)
{
    (void)in_sizes; (void)n_in; (void)out_size; (void)ws_size;
    const float* e2       = (const float*)d_in[0];
    const int*   iidx     = (const int*)d_in[1];
    const float* afe      = (const float*)d_in[2];
    const int*   bei      = (const int*)d_in[3];
    const float* battr    = (const float*)d_in[4];
    const float* lin_v_w  = (const float*)d_in[5];
    const float* lin_v_b  = (const float*)d_in[6];
    const float* conv_w   = (const float*)d_in[7];
    const float* w1       = (const float*)d_in[8];
    const float* b1       = (const float*)d_in[9];
    const float* w2       = (const float*)d_in[10];
    const float* b2       = (const float*)d_in[11];
    const float* lin_up_w = (const float*)d_in[12];
    const float* lin_up_b = (const float*)d_in[13];
    const float* lins_w   = (const float*)d_in[14];
    const float* lins_b   = (const float*)d_in[15];
    const float* lin_w    = (const float*)d_in[16];

    char* ws = (char*)d_ws;
    int2* edgep = (int2*)(ws + 0);
    u16*  Xh    = (u16*) (ws + 12800000);
    u16*  Xl    = (u16*) (ws + 28800000);
    u16*  s0h   = (u16*) (ws + 12800000);       // alias (Xcat dead by lin_up)
    u16*  s0l   = (u16*) (ws + 38400000);
    u16*  v1h   = (u16*) (ws + 64000000);
    u16*  v1l   = (u16*) (ws + 76800000);
    u16*  xw    = (u16*) (ws + 89600000);
    u16*  s1h   = (u16*) (ws + 64000000);       // alias (v1,xw dead by lins1)
    u16*  s1l   = (u16*) (ws + 89600000);
    float* ew   = (float*)(ws + 102400000);     // s1l tail; dead early
    int*   midx = (int*)  (ws + 108800000);     // s1l tail; dead early
    int*   cntC = (int*)  (ws + 115200000);
    int*   cntM = (int*)  (ws + 115400000);
    float* deg  = (float*)(ws + 115600000);
    int*   offC = (int*)  (ws + 115800000);
    int*   curC = (int*)  (ws + 116000064);
    int*   offM = (int*)  (ws + 116200064);
    int*   curM = (int*)  (ws + 116400128);
    float* dinv = (float*)(ws + 116600128);
    u16*   Wh   = (u16*)  (ws + 116800128);     // 266,240 elements
    u16*   Wl   = (u16*)  (ws + 117332608);
    int*   partC= (int*)  (ws + 117865088);
    int*   partM= (int*)  (ws + 117865872);

    // Wh/Wl element offsets per matrix:
    const int oWv = 0, oConv = 20480, oLup = 36864, oLins = 69632;

    hipMemsetAsync(ws + 115200000, 0, 3 * Nn * 4, stream);   // cntC,cntM,deg
    hipMemsetAsync(d_out, 0, Nn * 4, stream);                // fused-final acc

    k_edge<<<(Ee + 255) / 256, 256, 0, stream>>>(battr, bei, w1, b1, w2, b2,
                                                 ew, deg, cntC, iidx, cntM);
    k_scanA<<<dim3(NB, 2), 256, 0, stream>>>(cntC, offC, partC,
                                             cntM, offM, partM);
    k_scanB<<<2, 256, 0, stream>>>(partC, partM);
    k_scanC<<<dim3(NB, 2), 256, 0, stream>>>(cntC, partC, offC, curC,
                                             cntM, partM, offM, curM,
                                             deg, dinv);
    k_scatter<<<(Ee + 255) / 256, 256, 0, stream>>>(bei, ew, dinv, curC,
                                                    edgep, iidx, curM, midx);
    k_segsum<<<(Nn + 3) / 4, 256, 0, stream>>>(offM, midx, e2, afe, Xh, Xl);
    k_splitw_all<<<(266240 + 255) / 256, 256, 0, stream>>>(
        lin_v_w, conv_w, lin_up_w, lins_w, Wh, Wl);

#define GEMM(AH, AL, WO, BP, YH, YL, LW, OV, M_, K_, NO_, FL_)                \
    k_gemm<<<dim3(((M_) + 127) / 128, (NO_) / 128), 256, 0, stream>>>(        \
        AH, AL, Wh + (WO), Wl + (WO), (const float*)(BP),                     \
        YH, YL, (const float*)(LW), (float*)(OV), M_, K_, NO_, FL_)

    GEMM(Xh, Xl, oWv, lin_v_b, v1h, v1l, nullptr, nullptr, Nn, 160, 128, 2);
    GEMM(v1h, v1l, oConv, nullptr, xw, nullptr, nullptr, nullptr,
         Nn, 128, 128, 0);                                     // xw1 bf16
    k_gather<<<(Nn + 3) / 4, 256, 0, stream>>>(offC, edgep, xw, v1h, v1l, 0);
    GEMM(v1h, v1l, oConv, nullptr, xw, nullptr, nullptr, nullptr,
         Nn, 128, 128, 0);                                     // xw2 bf16
    k_gather<<<(Nn + 3) / 4, 256, 0, stream>>>(offC, edgep, xw, v1h, v1l, 1);
    GEMM(v1h, v1l, oLup, lin_up_b, s0h, s0l, nullptr, nullptr,
         Nn, 128, 256, 2);                                     // lin_up
    GEMM(s0h, s0l, oLins + 0 * 65536, lins_b + 0,   s1h, s1l, nullptr, nullptr,
         Nn, 256, 256, 3);
    GEMM(s1h, s1l, oLins + 1 * 65536, lins_b + 256, s0h, s0l, nullptr, nullptr,
         Nn, 256, 256, 3);
    GEMM(s0h, s0l, oLins + 2 * 65536, lins_b + 512, nullptr, nullptr,
         lin_w, d_out, Nn, 256, 256, 5);                       // fused final
#undef GEMM
}